// Round 3
// baseline (350.731 us; speedup 1.0000x reference)
//
#include <hip/hip_runtime.h>
#include <hip/hip_bf16.h>

// Diagonal-MVN negative mean log-prob:
//   loss = (0.5/B) * [ sum_all((t-mu)^2/sigma) + sum_all(log sigma) ] + 0.5*D*log(2*pi)
// B=16384, D=2048, all f32. Pure streaming reduction -> HBM-bound (~402 MB read).

#define LOG_2PI 1.8378770664093453f

__global__ __launch_bounds__(256) void mvn_nll_kernel(
    const float* __restrict__ mu,
    const float* __restrict__ sigma,
    const float* __restrict__ target,
    float* __restrict__ out,
    long long n4,           // total elements / 4
    float scale,            // 0.5 / B
    float const_term)       // 0.5 * D * LOG_2PI (added by block 0 only)
{
    const float4* __restrict__ mu4 = reinterpret_cast<const float4*>(mu);
    const float4* __restrict__ sg4 = reinterpret_cast<const float4*>(sigma);
    const float4* __restrict__ tg4 = reinterpret_cast<const float4*>(target);

    long long idx    = (long long)blockIdx.x * blockDim.x + threadIdx.x;
    long long stride = (long long)gridDim.x * blockDim.x;

    float acc = 0.0f;
    for (long long i = idx; i < n4; i += stride) {
        float4 m = mu4[i];
        float4 s = sg4[i];
        float4 t = tg4[i];

        float d0 = t.x - m.x;
        float d1 = t.y - m.y;
        float d2 = t.z - m.z;
        float d3 = t.w - m.w;

        // quadratic term: d^2 * rcp(sigma)  (v_rcp_f32 approx, ~1 ulp; sigma in [0.5,1.5])
        float q = d0 * d0 * __builtin_amdgcn_rcpf(s.x);
        q      += d1 * d1 * __builtin_amdgcn_rcpf(s.y);
        q      += d2 * d2 * __builtin_amdgcn_rcpf(s.z);
        q      += d3 * d3 * __builtin_amdgcn_rcpf(s.w);

        // logdet term: log(prod of 4 sigmas) -> 1 v_log_f32 per 4 elements.
        // prod in [0.0625, 5.0625] -- safely representable.
        float p = (s.x * s.y) * (s.z * s.w);
        acc += q + __logf(p);
    }

    // wave (64-lane) butterfly reduce
    #pragma unroll
    for (int off = 32; off > 0; off >>= 1)
        acc += __shfl_down(acc, off, 64);

    __shared__ float smem[4];  // 256 threads / 64 = 4 waves
    int wave = threadIdx.x >> 6;
    if ((threadIdx.x & 63) == 0) smem[wave] = acc;
    __syncthreads();

    if (threadIdx.x == 0) {
        float bsum = smem[0] + smem[1] + smem[2] + smem[3];
        float contrib = bsum * scale;           // pre-scale: atomic sum ~O(4000), no cancellation
        if (blockIdx.x == 0) contrib += const_term;
        atomicAdd(out, contrib);
    }
}

extern "C" void kernel_launch(void* const* d_in, const int* in_sizes, int n_in,
                              void* d_out, int out_size, void* d_ws, size_t ws_size,
                              hipStream_t stream) {
    const float* mu     = (const float*)d_in[0];
    const float* sigma  = (const float*)d_in[1];
    const float* target = (const float*)d_in[2];
    float* out = (float*)d_out;

    const long long D = 2048;
    const long long n = (long long)in_sizes[0];   // B * D (16384 * 2048)
    const long long B = n / D;
    const long long n4 = n / 4;

    // d_out is re-poisoned to 0xAA before every timed replay -> zero it on-stream.
    hipMemsetAsync(d_out, 0, (size_t)out_size * sizeof(float), stream);

    const int block = 256;
    const int grid  = 2048;  // memory-bound: cap at ~8 blocks/CU, grid-stride the rest

    float scale      = 0.5f / (float)B;
    float const_term = 0.5f * (float)D * LOG_2PI;

    mvn_nll_kernel<<<grid, block, 0, stream>>>(mu, sigma, target, out, n4, scale, const_term);
}